// Round 3
// baseline (844.719 us; speedup 1.0000x reference)
//
#include <hip/hip_runtime.h>
#include <hip/hip_bf16.h>

#define N_NODES 100000
#define N_EDGES 1000000
#define DIM 64

static const long long ND = (long long)N_NODES * DIM;  // 6,400,000

// d_out layout (floats):
// h1: [0, ND)  h2: [ND, 2*ND)  c1c2: [2*ND, 2*ND+128)  h3: [2*ND+128, ...)  h4: [3*ND+128, ...)

// d_ws layout (4-byte units):
#define WS_CURSOR1 0
#define WS_CURSOR2 100000
#define WS_OFF1    200000
#define WS_OFF2    300001
#define WS_SORTED1 400002
#define WS_SORTED2 1400002
#define WS_CSUM    2400002            // 128 floats
#define WS_FEATB   2400130            // bf16 feat rows, ND/2 u32 words = 3.2M
#define WS_SHUFB   5600130
#define WS_END     8800130            // *4B = 35.2 MB

__device__ __forceinline__ unsigned pk_bf16(float a, float b) {
    __hip_bfloat16 ha = __float2bfloat16(a), hb = __float2bfloat16(b);
    return (unsigned)(*(unsigned short*)&ha) | ((unsigned)(*(unsigned short*)&hb) << 16);
}

// Zero cursors + csum; optionally convert feat/shuf to bf16 rows in ws.
__global__ __launch_bounds__(256) void k_init(int* __restrict__ ws,
                                              const float4* __restrict__ feat4,
                                              const float4* __restrict__ shuf4,
                                              int do_conv) {
    long long i = (long long)blockIdx.x * blockDim.x + threadIdx.x;
    long long stride = (long long)gridDim.x * blockDim.x;
    for (long long j = i; j < 200000; j += stride) ws[j] = 0;
    if (i < 128) ((float*)ws)[WS_CSUM + i] = 0.f;
    if (do_conv) {
        uint2* featb = (uint2*)(ws + WS_FEATB);
        uint2* shufb = (uint2*)(ws + WS_SHUFB);
        const long long n4 = ND / 4;  // 1.6M float4s per array
        for (long long j = i; j < n4; j += stride) {
            float4 f = feat4[j];
            featb[j] = make_uint2(pk_bf16(f.x, f.y), pk_bf16(f.z, f.w));
            float4 g = shuf4[j];
            shufb[j] = make_uint2(pk_bf16(g.x, g.y), pk_bf16(g.z, g.w));
        }
    }
}

__global__ __launch_bounds__(256) void k_hist(const int4* __restrict__ dst1,
                                              const int4* __restrict__ dst2,
                                              int* __restrict__ ws) {
    int i = blockIdx.x * blockDim.x + threadIdx.x;
    const int Q = N_EDGES / 4;
    if (i < Q) {
        int4 d = dst1[i];
        atomicAdd(&ws[WS_CURSOR1 + d.x], 1);
        atomicAdd(&ws[WS_CURSOR1 + d.y], 1);
        atomicAdd(&ws[WS_CURSOR1 + d.z], 1);
        atomicAdd(&ws[WS_CURSOR1 + d.w], 1);
    } else if (i < 2 * Q) {
        int4 d = dst2[i - Q];
        atomicAdd(&ws[WS_CURSOR2 + d.x], 1);
        atomicAdd(&ws[WS_CURSOR2 + d.y], 1);
        atomicAdd(&ws[WS_CURSOR2 + d.z], 1);
        atomicAdd(&ws[WS_CURSOR2 + d.w], 1);
    }
}

// One block per graph (blockIdx.y). 1024 threads scan 100K counts.
__global__ __launch_bounds__(1024) void k_scan(int* __restrict__ ws) {
    const int g = blockIdx.y;
    int* hist = ws + (g ? WS_CURSOR2 : WS_CURSOR1);
    int* off  = ws + (g ? WS_OFF2 : WS_OFF1);

    __shared__ int s[1024];
    const int t = threadIdx.x;
    const int CH = 98;
    int start = t * CH;
    int end = start + CH; if (end > N_NODES) end = N_NODES;

    int local = 0;
    for (int i = start; i < end; ++i) local += hist[i];
    s[t] = local;
    __syncthreads();
    for (int d = 1; d < 1024; d <<= 1) {
        int v = 0;
        if (t >= d) v = s[t - d];
        __syncthreads();
        if (t >= d) s[t] += v;
        __syncthreads();
    }
    int run = (t == 0) ? 0 : s[t - 1];
    for (int i = start; i < end; ++i) {
        int h = hist[i];
        off[i] = run;
        hist[i] = run;                 // cursor = start position
        run += h;
    }
    if (t == 1023) off[N_NODES] = s[1023];
}

__global__ __launch_bounds__(256) void k_fill(const int4* __restrict__ src1,
                                              const int4* __restrict__ dst1,
                                              const int4* __restrict__ src2,
                                              const int4* __restrict__ dst2,
                                              int* __restrict__ ws) {
    int i = blockIdx.x * blockDim.x + threadIdx.x;
    const int Q = N_EDGES / 4;
    if (i < Q) {
        int4 sv = src1[i]; int4 dv = dst1[i];
        int p0 = atomicAdd(&ws[WS_CURSOR1 + dv.x], 1); ws[WS_SORTED1 + p0] = sv.x;
        int p1 = atomicAdd(&ws[WS_CURSOR1 + dv.y], 1); ws[WS_SORTED1 + p1] = sv.y;
        int p2 = atomicAdd(&ws[WS_CURSOR1 + dv.z], 1); ws[WS_SORTED1 + p2] = sv.z;
        int p3 = atomicAdd(&ws[WS_CURSOR1 + dv.w], 1); ws[WS_SORTED1 + p3] = sv.w;
    } else if (i < 2 * Q) {
        int e = i - Q;
        int4 sv = src2[e]; int4 dv = dst2[e];
        int p0 = atomicAdd(&ws[WS_CURSOR2 + dv.x], 1); ws[WS_SORTED2 + p0] = sv.x;
        int p1 = atomicAdd(&ws[WS_CURSOR2 + dv.y], 1); ws[WS_SORTED2 + p1] = sv.y;
        int p2 = atomicAdd(&ws[WS_CURSOR2 + dv.z], 1); ws[WS_SORTED2 + p2] = sv.z;
        int p3 = atomicAdd(&ws[WS_CURSOR2 + dv.w], 1); ws[WS_SORTED2 + p3] = sv.w;
    }
}

// blockIdx.y = graph. 4 waves/block, 8 nodes/wave (serial). Within a wave:
// 4 edge-slots x 16 lanes; each lane loads 4 dims (8B bf16 or 16B f32).
// Cross-slot shfl_xor reduce, then readlane-broadcast 64x64 matmul (W in LDS).
template <int BF16P>
__global__ __launch_bounds__(256) void k_gather(int* __restrict__ ws,
                                                const float* __restrict__ feat,
                                                const float* __restrict__ shuf,
                                                const float* __restrict__ W1,
                                                const float* __restrict__ b1,
                                                const float* __restrict__ W2,
                                                const float* __restrict__ b2,
                                                float* __restrict__ out) {
    const int g = blockIdx.y;
    const int* off    = ws + (g ? WS_OFF2 : WS_OFF1);
    const int* sorted = ws + (g ? WS_SORTED2 : WS_SORTED1);
    const float* W    = g ? W2 : W1;
    const float* bias = g ? b2 : b1;
    float* h_f = out + (g ? ND : 0);
    float* h_s = out + (g ? 3 * ND + 128 : 2 * ND + 128);
    float* csum = (float*)ws + WS_CSUM + g * 64;

    __shared__ float Wl[64 * 64];
    __shared__ float red[4][64];

    const int t = threadIdx.x;
    for (int i = t; i < 64 * 64; i += 256) Wl[i] = W[i];
    __syncthreads();

    const int wave = t >> 6;
    const int lane = t & 63;
    const int slot = lane >> 4;
    const int sub  = lane & 15;

    const uint2* featb = (const uint2*)(ws + WS_FEATB);
    const uint2* shufb = (const uint2*)(ws + WS_SHUFB);
    const float4* feat4 = (const float4*)feat;
    const float4* shuf4 = (const float4*)shuf;

    const float bj = bias[lane];
    float csum_acc = 0.f;
    const int nb = blockIdx.x * 32 + wave * 8;

    for (int r = 0; r < 8; ++r) {
        const int n = nb + r;
        if (n >= N_NODES) break;
        const int e0 = off[n];
        const int e1 = off[n + 1];

        float af0 = 0.f, af1 = 0.f, af2 = 0.f, af3 = 0.f;
        float as0 = 0.f, as1 = 0.f, as2 = 0.f, as3 = 0.f;
        for (int e = e0 + slot; e < e1; e += 4) {
            const int s = sorted[e];
            if (BF16P) {
                const uint2 uf = featb[s * 16 + sub];
                const uint2 us_ = shufb[s * 16 + sub];
                af0 += __uint_as_float(uf.x << 16);
                af1 += __uint_as_float(uf.x & 0xFFFF0000u);
                af2 += __uint_as_float(uf.y << 16);
                af3 += __uint_as_float(uf.y & 0xFFFF0000u);
                as0 += __uint_as_float(us_.x << 16);
                as1 += __uint_as_float(us_.x & 0xFFFF0000u);
                as2 += __uint_as_float(us_.y << 16);
                as3 += __uint_as_float(us_.y & 0xFFFF0000u);
            } else {
                const float4 f = feat4[s * 16 + sub];
                const float4 h = shuf4[s * 16 + sub];
                af0 += f.x; af1 += f.y; af2 += f.z; af3 += f.w;
                as0 += h.x; as1 += h.y; as2 += h.z; as3 += h.w;
            }
        }
        // reduce across the 4 slots: lanes {l, l^16, l^32, l^48} hold same dims
        af0 += __shfl_xor(af0, 16); af0 += __shfl_xor(af0, 32);
        af1 += __shfl_xor(af1, 16); af1 += __shfl_xor(af1, 32);
        af2 += __shfl_xor(af2, 16); af2 += __shfl_xor(af2, 32);
        af3 += __shfl_xor(af3, 16); af3 += __shfl_xor(af3, 32);
        as0 += __shfl_xor(as0, 16); as0 += __shfl_xor(as0, 32);
        as1 += __shfl_xor(as1, 16); as1 += __shfl_xor(as1, 32);
        as2 += __shfl_xor(as2, 16); as2 += __shfl_xor(as2, 32);
        as3 += __shfl_xor(as3, 16); as3 += __shfl_xor(as3, 32);

        // lane k (k<16) holds agg dims 4k..4k+3; broadcast and FMA
        float hf = bj, hs = bj;
        #pragma unroll
        for (int k = 0; k < 16; ++k) {
            const float f0 = __shfl(af0, k), f1 = __shfl(af1, k),
                        f2 = __shfl(af2, k), f3 = __shfl(af3, k);
            const float s0 = __shfl(as0, k), s1 = __shfl(as1, k),
                        s2 = __shfl(as2, k), s3 = __shfl(as3, k);
            const float w0 = Wl[(4 * k + 0) * 64 + lane];
            const float w1 = Wl[(4 * k + 1) * 64 + lane];
            const float w2 = Wl[(4 * k + 2) * 64 + lane];
            const float w3 = Wl[(4 * k + 3) * 64 + lane];
            hf += f0 * w0 + f1 * w1 + f2 * w2 + f3 * w3;
            hs += s0 * w0 + s1 * w1 + s2 * w2 + s3 * w3;
        }
        h_f[(long long)n * DIM + lane] = hf;
        h_s[(long long)n * DIM + lane] = hs;
        csum_acc += hf;
    }

    red[wave][lane] = csum_acc;
    __syncthreads();
    if (wave == 0) {
        float s4 = red[0][lane] + red[1][lane] + red[2][lane] + red[3][lane];
        unsafeAtomicAdd(&csum[lane], s4);
    }
}

__global__ void k_final(const float* __restrict__ ws_csum, float* __restrict__ out_c) {
    int t = threadIdx.x;  // 0..63 -> c1, 64..127 -> c2
    float m = ws_csum[t] * (1.0f / (float)N_NODES);
    out_c[t] = 1.f / (1.f + expf(-m));
}

extern "C" void kernel_launch(void* const* d_in, const int* in_sizes, int n_in,
                              void* d_out, int out_size, void* d_ws, size_t ws_size,
                              hipStream_t stream) {
    const float* feat = (const float*)d_in[0];
    const float* shuf = (const float*)d_in[1];
    const int* src1 = (const int*)d_in[2];
    const int* dst1 = (const int*)d_in[3];
    const int* src2 = (const int*)d_in[4];
    const int* dst2 = (const int*)d_in[5];
    const float* W1 = (const float*)d_in[6];
    const float* b1 = (const float*)d_in[7];
    const float* W2 = (const float*)d_in[8];
    const float* b2 = (const float*)d_in[9];

    float* out = (float*)d_out;
    int* ws = (int*)d_ws;
    float* c_out = out + 2 * ND;

    const bool use_bf16 = ws_size >= (size_t)WS_END * 4;

    k_init<<<1600, 256, 0, stream>>>(ws, (const float4*)feat, (const float4*)shuf,
                                     use_bf16 ? 1 : 0);
    k_hist<<<(2 * (N_EDGES / 4) + 255) / 256, 256, 0, stream>>>(
        (const int4*)dst1, (const int4*)dst2, ws);
    k_scan<<<dim3(1, 2), 1024, 0, stream>>>(ws);
    k_fill<<<(2 * (N_EDGES / 4) + 255) / 256, 256, 0, stream>>>(
        (const int4*)src1, (const int4*)dst1, (const int4*)src2, (const int4*)dst2, ws);

    dim3 tgrid((N_NODES + 31) / 32, 2);
    if (use_bf16)
        k_gather<1><<<tgrid, 256, 0, stream>>>(ws, feat, shuf, W1, b1, W2, b2, out);
    else
        k_gather<0><<<tgrid, 256, 0, stream>>>(ws, feat, shuf, W1, b1, W2, b2, out);

    k_final<<<1, 128, 0, stream>>>((const float*)ws + WS_CSUM, c_out);
}

// Round 4
// 560.935 us; speedup vs baseline: 1.5059x; 1.5059x over previous
//
#include <hip/hip_runtime.h>
#include <hip/hip_bf16.h>

#define N_NODES 100000
#define N_EDGES 1000000
#define DIM 64

static const long long ND = (long long)N_NODES * DIM;  // 6,400,000

// d_out layout (floats):
// h1: [0, ND)  h2: [ND, 2*ND)  c1c2: [2*ND, 2*ND+128)  h3: [2*ND+128, ...)  h4: [3*ND+128, ...)

// d_ws layout (4-byte words, all region bases %4 == 0 for int4/uint4 access):
#define WS_CUR1  0
#define WS_CUR2  100000
#define WS_OFF1  200000            // 100001 used, padded to 100004
#define WS_OFF2  300004
#define WS_SORT1 400008
#define WS_SORT2 1400008
#define WS_CSUM  2400008           // 128 floats
#define WS_BSUM  2400136           // 196 ints (2 graphs x 98 blocks)
#define WS_T1    2400512           // bf16 [G|S] rows, 64 words/row, 6.4M words
#define WS_T2    (WS_T1 + 6400000)
#define WS_END   (WS_T2 + 6400000) // 15,200,512 words = ~58 MB

#define SCAN_BLOCKS 98             // 98 * 1024 >= 100000

__device__ __forceinline__ unsigned pk_bf16(float a, float b) {
    __hip_bfloat16 ha = __float2bfloat16(a), hb = __float2bfloat16(b);
    return (unsigned)(*(unsigned short*)&ha) | ((unsigned)(*(unsigned short*)&hb) << 16);
}
__device__ __forceinline__ float bf_lo(unsigned u) { return __uint_as_float(u << 16); }
__device__ __forceinline__ float bf_hi(unsigned u) { return __uint_as_float(u & 0xFFFF0000u); }

__global__ __launch_bounds__(256) void k_init(int* __restrict__ ws) {
    int i = blockIdx.x * blockDim.x + threadIdx.x;
    if (i < 200000) ws[i] = 0;                                   // cursors (= histograms)
    else if (i < 200128) ((float*)ws)[WS_CSUM + (i - 200000)] = 0.f;
    else if (i == 200128) {
        ws[WS_OFF1 + N_NODES] = N_EDGES;
        ws[WS_OFF2 + N_NODES] = N_EDGES;
    }
}

__global__ __launch_bounds__(256) void k_hist(const int4* __restrict__ dst1,
                                              const int4* __restrict__ dst2,
                                              int* __restrict__ ws) {
    int i = blockIdx.x * blockDim.x + threadIdx.x;
    const int Q = N_EDGES / 4;
    if (i < Q) {
        int4 d = dst1[i];
        atomicAdd(&ws[WS_CUR1 + d.x], 1);
        atomicAdd(&ws[WS_CUR1 + d.y], 1);
        atomicAdd(&ws[WS_CUR1 + d.z], 1);
        atomicAdd(&ws[WS_CUR1 + d.w], 1);
    } else if (i < 2 * Q) {
        int4 d = dst2[i - Q];
        atomicAdd(&ws[WS_CUR2 + d.x], 1);
        atomicAdd(&ws[WS_CUR2 + d.y], 1);
        atomicAdd(&ws[WS_CUR2 + d.z], 1);
        atomicAdd(&ws[WS_CUR2 + d.w], 1);
    }
}

// Phase 1: per-block sums of 1024 counts -> bsum[g*98+b]
__global__ __launch_bounds__(256) void k_scan1(int* __restrict__ ws) {
    const int g = blockIdx.y;
    const int* hist = ws + (g ? WS_CUR2 : WS_CUR1);
    const int t = threadIdx.x;
    const int base = blockIdx.x * 1024 + t * 4;
    int4 c = make_int4(0, 0, 0, 0);
    if (base < N_NODES) c = *(const int4*)(hist + base);
    __shared__ int s[256];
    s[t] = c.x + c.y + c.z + c.w;
    __syncthreads();
    for (int d = 128; d > 0; d >>= 1) {
        if (t < d) s[t] += s[t + d];
        __syncthreads();
    }
    if (t == 0) ws[WS_BSUM + g * SCAN_BLOCKS + blockIdx.x] = s[0];
}

// Phase 2: one block scans the 196 block sums (two independent 98-segments), exclusive.
__global__ __launch_bounds__(256) void k_scan2(int* __restrict__ ws) {
    const int t = threadIdx.x;
    const int n = 2 * SCAN_BLOCKS;
    __shared__ int s[256];
    s[t] = (t < n) ? ws[WS_BSUM + t] : 0;
    __syncthreads();
    for (int d = 1; d < 256; d <<= 1) {
        int v = 0;
        if (t >= d && (t < SCAN_BLOCKS || t - d >= SCAN_BLOCKS)) v = s[t - d];
        __syncthreads();
        s[t] += v;
        __syncthreads();
    }
    if (t < n) {
        int excl = (t == 0 || t == SCAN_BLOCKS) ? 0 : s[t - 1];
        ws[WS_BSUM + t] = excl;
    }
}

// Phase 3: local exclusive scan + block offset -> off[] and cursor[]
__global__ __launch_bounds__(256) void k_scan3(int* __restrict__ ws) {
    const int g = blockIdx.y;
    int* cur = ws + (g ? WS_CUR2 : WS_CUR1);
    int* off = ws + (g ? WS_OFF2 : WS_OFF1);
    const int t = threadIdx.x;
    const int base = blockIdx.x * 1024 + t * 4;
    int4 c = make_int4(0, 0, 0, 0);
    if (base < N_NODES) c = *(const int4*)(cur + base);
    __shared__ int s[256];
    s[t] = c.x + c.y + c.z + c.w;
    __syncthreads();
    for (int d = 1; d < 256; d <<= 1) {
        int v = 0;
        if (t >= d) v = s[t - d];
        __syncthreads();
        s[t] += v;
        __syncthreads();
    }
    int excl = (t == 0) ? 0 : s[t - 1];
    int boff = ws[WS_BSUM + g * SCAN_BLOCKS + blockIdx.x];
    if (base < N_NODES) {
        int o0 = boff + excl;
        int o1 = o0 + c.x, o2 = o1 + c.y, o3 = o2 + c.z;
        int4 o = make_int4(o0, o1, o2, o3);
        *(int4*)(off + base) = o;
        *(int4*)(cur + base) = o;
    }
}

__global__ __launch_bounds__(256) void k_fill(const int4* __restrict__ src1,
                                              const int4* __restrict__ dst1,
                                              const int4* __restrict__ src2,
                                              const int4* __restrict__ dst2,
                                              int* __restrict__ ws) {
    int i = blockIdx.x * blockDim.x + threadIdx.x;
    const int Q = N_EDGES / 4;
    if (i < Q) {
        int4 sv = src1[i]; int4 dv = dst1[i];
        int p0 = atomicAdd(&ws[WS_CUR1 + dv.x], 1); ws[WS_SORT1 + p0] = sv.x;
        int p1 = atomicAdd(&ws[WS_CUR1 + dv.y], 1); ws[WS_SORT1 + p1] = sv.y;
        int p2 = atomicAdd(&ws[WS_CUR1 + dv.z], 1); ws[WS_SORT1 + p2] = sv.z;
        int p3 = atomicAdd(&ws[WS_CUR1 + dv.w], 1); ws[WS_SORT1 + p3] = sv.w;
    } else if (i < 2 * Q) {
        int e = i - Q;
        int4 sv = src2[e]; int4 dv = dst2[e];
        int p0 = atomicAdd(&ws[WS_CUR2 + dv.x], 1); ws[WS_SORT2 + p0] = sv.x;
        int p1 = atomicAdd(&ws[WS_CUR2 + dv.y], 1); ws[WS_SORT2 + p1] = sv.y;
        int p2 = atomicAdd(&ws[WS_CUR2 + dv.z], 1); ws[WS_SORT2 + p2] = sv.z;
        int p3 = atomicAdd(&ws[WS_CUR2 + dv.w], 1); ws[WS_SORT2 + p3] = sv.w;
    }
}

// Pre-transform: T_g[n] = [bf16(feat[n]@W_g) | bf16(shuf[n]@W_g)], 256B/row.
// Thread-per-row; blockIdx.y: g = y>>1, br = y&1 (0=feat->G half, 1=shuf->S half).
// NO bias here (bias added once after aggregation).
__global__ __launch_bounds__(256) void k_transform(int* __restrict__ ws,
                                                   const float* __restrict__ feat,
                                                   const float* __restrict__ shuf,
                                                   const float* __restrict__ W1,
                                                   const float* __restrict__ W2) {
    const int g = blockIdx.y >> 1;
    const int br = blockIdx.y & 1;
    const float* W = g ? W2 : W1;
    const float* src = br ? shuf : feat;

    __shared__ float Wl[64 * 64];
    const int t = threadIdx.x;
    for (int i = t; i < 64 * 64; i += 256) Wl[i] = W[i];
    __syncthreads();

    const int n = blockIdx.x * 256 + t;
    if (n >= N_NODES) return;

    float a[64];
    const float4* a4 = (const float4*)(src + (long long)n * DIM);
    #pragma unroll
    for (int i = 0; i < 16; ++i) {
        float4 v = a4[i];
        a[4 * i + 0] = v.x; a[4 * i + 1] = v.y; a[4 * i + 2] = v.z; a[4 * i + 3] = v.w;
    }

    unsigned* Trow = (unsigned*)(ws + (g ? WS_T2 : WS_T1)) + n * 64 + br * 32;
    const float4* W4 = (const float4*)Wl;

    #pragma unroll
    for (int jb = 0; jb < 8; ++jb) {
        float acc[8] = {0.f, 0.f, 0.f, 0.f, 0.f, 0.f, 0.f, 0.f};
        #pragma unroll
        for (int k = 0; k < 64; ++k) {
            float4 w0 = W4[k * 16 + jb * 2];
            float4 w1 = W4[k * 16 + jb * 2 + 1];
            float ak = a[k];
            acc[0] += ak * w0.x; acc[1] += ak * w0.y;
            acc[2] += ak * w0.z; acc[3] += ak * w0.w;
            acc[4] += ak * w1.x; acc[5] += ak * w1.y;
            acc[6] += ak * w1.z; acc[7] += ak * w1.w;
        }
        uint4 p;
        p.x = pk_bf16(acc[0], acc[1]);
        p.y = pk_bf16(acc[2], acc[3]);
        p.z = pk_bf16(acc[4], acc[5]);
        p.w = pk_bf16(acc[6], acc[7]);
        ((uint4*)Trow)[jb] = p;
    }
}

// Gather-aggregate pre-transformed rows. blockIdx.y = graph.
// 4 waves/block, 8 nodes/wave serial. 4 edge-slots x 16 lanes x uint4 (full 256B row).
// sub<8 lanes accumulate G dims [8sub..8sub+8); sub>=8 accumulate S dims [8(sub-8)..).
__global__ __launch_bounds__(256) void k_gather_pre(int* __restrict__ ws,
                                                    const float* __restrict__ b1,
                                                    const float* __restrict__ b2,
                                                    float* __restrict__ out) {
    const int g = blockIdx.y;
    const int* off    = ws + (g ? WS_OFF2 : WS_OFF1);
    const int* sorted = ws + (g ? WS_SORT2 : WS_SORT1);
    const uint4* T = (const uint4*)(ws + (g ? WS_T2 : WS_T1));   // 16 uint4 per row
    const float* bias = g ? b2 : b1;
    float* h_f = out + (g ? ND : 0);
    float* h_s = out + (g ? 3 * ND + 128 : 2 * ND + 128);
    float* csum = (float*)ws + WS_CSUM + g * 64;

    const int t = threadIdx.x;
    const int wave = t >> 6;
    const int lane = t & 63;
    const int slot = lane >> 4;
    const int sub = lane & 15;

    float bias8[8];
    #pragma unroll
    for (int i = 0; i < 8; ++i) bias8[i] = bias[(sub & 7) * 8 + i];

    __shared__ float red[4][8][8];
    float csum_acc[8] = {0.f, 0.f, 0.f, 0.f, 0.f, 0.f, 0.f, 0.f};

    const int nb = blockIdx.x * 32 + wave * 8;
    for (int r = 0; r < 8; ++r) {
        const int n = nb + r;
        if (n >= N_NODES) break;
        const int e0 = off[n];
        const int e1 = off[n + 1];

        float acc[8] = {0.f, 0.f, 0.f, 0.f, 0.f, 0.f, 0.f, 0.f};
        for (int e = e0 + slot; e < e1; e += 4) {
            const int s = sorted[e];
            const uint4 v = T[s * 16 + sub];
            acc[0] += bf_lo(v.x); acc[1] += bf_hi(v.x);
            acc[2] += bf_lo(v.y); acc[3] += bf_hi(v.y);
            acc[4] += bf_lo(v.z); acc[5] += bf_hi(v.z);
            acc[6] += bf_lo(v.w); acc[7] += bf_hi(v.w);
        }
        #pragma unroll
        for (int i = 0; i < 8; ++i) {
            acc[i] += __shfl_xor(acc[i], 16);
            acc[i] += __shfl_xor(acc[i], 32);
            acc[i] += bias8[i];
        }
        if (slot == 0 && sub < 8) {
            float* p = h_f + (long long)n * DIM + sub * 8;
            *(float4*)(p)     = make_float4(acc[0], acc[1], acc[2], acc[3]);
            *(float4*)(p + 4) = make_float4(acc[4], acc[5], acc[6], acc[7]);
            #pragma unroll
            for (int i = 0; i < 8; ++i) csum_acc[i] += acc[i];
        } else if (slot == 1 && sub >= 8) {
            float* p = h_s + (long long)n * DIM + (sub - 8) * 8;
            *(float4*)(p)     = make_float4(acc[0], acc[1], acc[2], acc[3]);
            *(float4*)(p + 4) = make_float4(acc[4], acc[5], acc[6], acc[7]);
        }
    }

    if (slot == 0 && sub < 8) {
        #pragma unroll
        for (int i = 0; i < 8; ++i) red[wave][sub][i] = csum_acc[i];
    }
    __syncthreads();
    if (t < 64) {
        int su = t >> 3, i = t & 7;
        float s4 = red[0][su][i] + red[1][su][i] + red[2][su][i] + red[3][su][i];
        unsafeAtomicAdd(&csum[su * 8 + i], s4);
    }
}

// Legacy fallback (small ws): f32 gather + in-kernel shfl matmul (R3 structure).
__global__ __launch_bounds__(256) void k_gather_legacy(int* __restrict__ ws,
                                                       const float* __restrict__ feat,
                                                       const float* __restrict__ shuf,
                                                       const float* __restrict__ W1,
                                                       const float* __restrict__ b1,
                                                       const float* __restrict__ W2,
                                                       const float* __restrict__ b2,
                                                       float* __restrict__ out) {
    const int g = blockIdx.y;
    const int* off    = ws + (g ? WS_OFF2 : WS_OFF1);
    const int* sorted = ws + (g ? WS_SORT2 : WS_SORT1);
    const float* W    = g ? W2 : W1;
    const float* bias = g ? b2 : b1;
    float* h_f = out + (g ? ND : 0);
    float* h_s = out + (g ? 3 * ND + 128 : 2 * ND + 128);
    float* csum = (float*)ws + WS_CSUM + g * 64;

    __shared__ float Wl[64 * 64];
    __shared__ float red[4][64];
    const int t = threadIdx.x;
    for (int i = t; i < 64 * 64; i += 256) Wl[i] = W[i];
    __syncthreads();

    const int wave = t >> 6;
    const int lane = t & 63;
    const int slot = lane >> 4;
    const int sub = lane & 15;
    const float4* feat4 = (const float4*)feat;
    const float4* shuf4 = (const float4*)shuf;
    const float bj = bias[lane];
    float csum_acc = 0.f;
    const int nb = blockIdx.x * 32 + wave * 8;

    for (int r = 0; r < 8; ++r) {
        const int n = nb + r;
        if (n >= N_NODES) break;
        const int e0 = off[n], e1 = off[n + 1];
        float af0 = 0.f, af1 = 0.f, af2 = 0.f, af3 = 0.f;
        float as0 = 0.f, as1 = 0.f, as2 = 0.f, as3 = 0.f;
        for (int e = e0 + slot; e < e1; e += 4) {
            const int s = sorted[e];
            const float4 f = feat4[s * 16 + sub];
            const float4 h = shuf4[s * 16 + sub];
            af0 += f.x; af1 += f.y; af2 += f.z; af3 += f.w;
            as0 += h.x; as1 += h.y; as2 += h.z; as3 += h.w;
        }
        af0 += __shfl_xor(af0, 16); af0 += __shfl_xor(af0, 32);
        af1 += __shfl_xor(af1, 16); af1 += __shfl_xor(af1, 32);
        af2 += __shfl_xor(af2, 16); af2 += __shfl_xor(af2, 32);
        af3 += __shfl_xor(af3, 16); af3 += __shfl_xor(af3, 32);
        as0 += __shfl_xor(as0, 16); as0 += __shfl_xor(as0, 32);
        as1 += __shfl_xor(as1, 16); as1 += __shfl_xor(as1, 32);
        as2 += __shfl_xor(as2, 16); as2 += __shfl_xor(as2, 32);
        as3 += __shfl_xor(as3, 16); as3 += __shfl_xor(as3, 32);
        float hf = bj, hs = bj;
        #pragma unroll
        for (int k = 0; k < 16; ++k) {
            const float f0 = __shfl(af0, k), f1 = __shfl(af1, k),
                        f2 = __shfl(af2, k), f3 = __shfl(af3, k);
            const float s0 = __shfl(as0, k), s1 = __shfl(as1, k),
                        s2 = __shfl(as2, k), s3 = __shfl(as3, k);
            const float w0 = Wl[(4 * k + 0) * 64 + lane];
            const float w1 = Wl[(4 * k + 1) * 64 + lane];
            const float w2 = Wl[(4 * k + 2) * 64 + lane];
            const float w3 = Wl[(4 * k + 3) * 64 + lane];
            hf += f0 * w0 + f1 * w1 + f2 * w2 + f3 * w3;
            hs += s0 * w0 + s1 * w1 + s2 * w2 + s3 * w3;
        }
        h_f[(long long)n * DIM + lane] = hf;
        h_s[(long long)n * DIM + lane] = hs;
        csum_acc += hf;
    }
    red[wave][lane] = csum_acc;
    __syncthreads();
    if (wave == 0) {
        float s4 = red[0][lane] + red[1][lane] + red[2][lane] + red[3][lane];
        unsafeAtomicAdd(&csum[lane], s4);
    }
}

__global__ void k_final(const float* __restrict__ ws_csum, float* __restrict__ out_c) {
    int t = threadIdx.x;  // 0..63 -> c1, 64..127 -> c2
    float m = ws_csum[t] * (1.0f / (float)N_NODES);
    out_c[t] = 1.f / (1.f + expf(-m));
}

extern "C" void kernel_launch(void* const* d_in, const int* in_sizes, int n_in,
                              void* d_out, int out_size, void* d_ws, size_t ws_size,
                              hipStream_t stream) {
    const float* feat = (const float*)d_in[0];
    const float* shuf = (const float*)d_in[1];
    const int* src1 = (const int*)d_in[2];
    const int* dst1 = (const int*)d_in[3];
    const int* src2 = (const int*)d_in[4];
    const int* dst2 = (const int*)d_in[5];
    const float* W1 = (const float*)d_in[6];
    const float* b1 = (const float*)d_in[7];
    const float* W2 = (const float*)d_in[8];
    const float* b2 = (const float*)d_in[9];

    float* out = (float*)d_out;
    int* ws = (int*)d_ws;
    float* c_out = out + 2 * ND;

    const bool use_pre = ws_size >= (size_t)WS_END * 4;

    k_init<<<(200129 + 255) / 256, 256, 0, stream>>>(ws);
    k_hist<<<(2 * (N_EDGES / 4) + 255) / 256, 256, 0, stream>>>(
        (const int4*)dst1, (const int4*)dst2, ws);
    k_scan1<<<dim3(SCAN_BLOCKS, 2), 256, 0, stream>>>(ws);
    k_scan2<<<1, 256, 0, stream>>>(ws);
    k_scan3<<<dim3(SCAN_BLOCKS, 2), 256, 0, stream>>>(ws);
    k_fill<<<(2 * (N_EDGES / 4) + 255) / 256, 256, 0, stream>>>(
        (const int4*)src1, (const int4*)dst1, (const int4*)src2, (const int4*)dst2, ws);

    if (use_pre) {
        k_transform<<<dim3((N_NODES + 255) / 256, 4), 256, 0, stream>>>(ws, feat, shuf, W1, W2);
        k_gather_pre<<<dim3((N_NODES + 31) / 32, 2), 256, 0, stream>>>(ws, b1, b2, out);
    } else {
        k_gather_legacy<<<dim3((N_NODES + 31) / 32, 2), 256, 0, stream>>>(
            ws, feat, shuf, W1, b1, W2, b2, out);
    }

    k_final<<<1, 128, 0, stream>>>((const float*)ws + WS_CSUM, c_out);
}